// Round 2
// baseline (174.895 us; speedup 1.0000x reference)
//
#include <hip/hip_runtime.h>

// Problem constants (fixed by the reference config)
#define BB     2
#define NN     4
#define CC     64
#define HF     64
#define WF     64
#define XVOX   128
#define YVOX   128
#define ZVOX   8
#define BN_TOT (BB * NN)                   // 8
#define FEATS_PER_BN (CC * HF * WF)        // 262144 floats
#define OUT_C_STRIDE (ZVOX * XVOX * YVOX)  // 131072
#define OUT_B_STRIDE (CC * OUT_C_STRIDE)   // 8388608

// ---------------------------------------------------------------------------
// Kernel 1: transpose feats NCHW -> NHWC so channels are contiguous.
// One block per (bn, h) row; LDS 64x65 tile kills bank conflicts.
// ---------------------------------------------------------------------------
__global__ __launch_bounds__(256) void transpose_feats_kernel(
    const float* __restrict__ in, float* __restrict__ outT) {
    __shared__ float tile[64 * 65];
    int bh = blockIdx.x;           // bn*64 + h
    int bn = bh >> 6;
    int h  = bh & 63;
    int t  = threadIdx.x;

    const float* src = in + bn * FEATS_PER_BN + h * WF;   // + c*4096 + w
#pragma unroll
    for (int k = 0; k < 16; ++k) {
        int idx = t + k * 256;     // 0..4095
        int c = idx >> 6;
        int w = idx & 63;
        tile[w * 65 + c] = src[c * (HF * WF) + w];        // coalesced read (w fastest)
    }
    __syncthreads();
    float* dst = outT + bn * FEATS_PER_BN + h * (WF * CC);  // + w*64 + c
#pragma unroll
    for (int k = 0; k < 16; ++k) {
        int idx = t + k * 256;
        int w = idx >> 6;
        int c = idx & 63;
        dst[w * CC + c] = tile[w * 65 + c];               // coalesced write (c fastest)
    }
}

// ---------------------------------------------------------------------------
// Kernel 2: main splat, channel-per-lane.
// Block = 256 threads = 4 waves; block handles 64 consecutive vy voxels.
// lane = channel -> every corner gather is ONE coalesced 256B load; all
// projection math is wave-uniform (scalar branches, no divergence).
// Results staged in LDS, then stored with 256B-coalesced channel planes.
// ---------------------------------------------------------------------------
__global__ __launch_bounds__(256) void bev_splat_kernel(
    const float* __restrict__ featsT,   // (BN, H, W, C)
    const float* __restrict__ intrins,  // (BN, 4, 4)
    const float* __restrict__ extrins,  // (BN, 4, 4)
    float* __restrict__ out) {
    __shared__ float tile[64 * 65];
    __shared__ float mats_s[NN * 12];

    int blk  = blockIdx.x;         // ((b*ZVOX+vz)*XVOX+vx)*2 + half
    int half = blk & 1;
    int vx   = (blk >> 1) & 127;
    int vz   = (blk >> 8) & 7;
    int b    = blk >> 11;

    // ---- compose this batch's 4 projection matrices (threads 0..3) ----
    if (threadIdx.x < NN) {
        int n  = threadIdx.x;
        int bn = b * NN + n;
        const float* e = extrins + bn * 16;
        const float* k = intrins + bn * 16;
        float inv[3][4];
#pragma unroll
        for (int i = 0; i < 3; ++i) {
            inv[i][0] = e[0 * 4 + i];
            inv[i][1] = e[1 * 4 + i];
            inv[i][2] = e[2 * 4 + i];
            inv[i][3] = -(e[0 * 4 + i] * e[0 * 4 + 3] +
                          e[1 * 4 + i] * e[1 * 4 + 3] +
                          e[2 * 4 + i] * e[2 * 4 + 3]);
        }
        float fx = k[0] * 0.125f;   // K[0,0] * sx (sx = 64/512 exact)
        float fy = k[5] * 0.125f;   // K[1,1] * sy
        float cx = k[2] * 0.125f;   // K[0,2] * sx
        float cy = k[6] * 0.125f;   // K[1,2] * sy
        float* m = mats_s + n * 12;
#pragma unroll
        for (int j = 0; j < 4; ++j) {
            m[j]     = fx * inv[0][j] + cx * inv[2][j];
            m[4 + j] = fy * inv[1][j] + cy * inv[2][j];
            m[8 + j] = inv[2][j];
        }
    }
    __syncthreads();

    int wave = threadIdx.x >> 6;
    int lane = threadIdx.x & 63;   // = channel
    int vy0  = half * 64;

    float xc = vx * 0.8f - 50.8f;
    float zc = vz * 0.5f - 2.75f;

    for (int i = 0; i < 16; ++i) {
        int v  = wave * 16 + i;    // local voxel 0..63
        int vy = vy0 + v;
        float yc = vy * 0.8f - 50.8f;

        float num = 0.0f;
        float cnt = 0.0f;
#pragma unroll
        for (int n = 0; n < NN; ++n) {
            const float* M = mats_s + n * 12;
            float px = M[0] * xc + M[1] * yc + M[2]  * zc + M[3];
            float py = M[4] * xc + M[5] * yc + M[6]  * zc + M[7];
            float pz = M[8] * xc + M[9] * yc + M[10] * zc + M[11];
            float denom = fmaxf(pz, 1e-6f);
            float sx = px / denom;
            float sy = py / denom;
            bool valid = (sx > -0.5f) && (sx < (float)WF - 0.5f) &&
                         (sy > -0.5f) && (sy < (float)HF - 0.5f) && (pz > 0.0f);
            if (!valid) continue;   // wave-uniform branch

            float gx = sx - 0.5f;
            float gy = sy - 0.5f;
            float x0f = floorf(gx), y0f = floorf(gy);
            float wx = gx - x0f,    wy = gy - y0f;
            int x0 = (int)x0f, y0 = (int)y0f;
            int   xs[2]  = {x0, x0 + 1};
            int   ys[2]  = {y0, y0 + 1};
            float wxs[2] = {1.0f - wx, wx};
            float wys[2] = {1.0f - wy, wy};
            const float* fb = featsT + (b * NN + n) * FEATS_PER_BN;

            float val = 0.0f;
#pragma unroll
            for (int ky = 0; ky < 2; ++ky) {
#pragma unroll
                for (int kx = 0; kx < 2; ++kx) {
                    int xi = xs[kx], yi = ys[ky];
                    bool cv = (xi >= 0) && (xi < WF) && (yi >= 0) && (yi < HF);
                    float w = cv ? (wxs[kx] * wys[ky]) : 0.0f;
                    if (w != 0.0f) {   // uniform; skipped term adds exact 0
                        val += w * fb[(yi * WF + xi) * CC + lane];  // 256B coalesced
                    }
                }
            }
            num += val;
            cnt += (val != 0.0f) ? 1.0f : 0.0f;
        }
        tile[v * 65 + lane] = num / (1e-6f + cnt);
    }
    __syncthreads();

    // ---- coalesced store: 64 consecutive vy per channel plane ----
    int base = b * OUT_B_STRIDE + vz * (XVOX * YVOX) + vx * YVOX + vy0;
#pragma unroll
    for (int it = 0; it < 16; ++it) {
        int idx = threadIdx.x + it * 256;
        int c = idx >> 6;
        int v = idx & 63;
        out[base + c * OUT_C_STRIDE + v] = tile[v * 65 + c];
    }
}

// ---------------------------------------------------------------------------
extern "C" void kernel_launch(void* const* d_in, const int* in_sizes, int n_in,
                              void* d_out, int out_size, void* d_ws, size_t ws_size,
                              hipStream_t stream) {
    const float* feats   = (const float*)d_in[0];   // (2,4,64,64,64)
    const float* intrins = (const float*)d_in[1];   // (2,4,4,4)
    const float* extrins = (const float*)d_in[2];   // (2,4,4,4)
    float* out = (float*)d_out;                     // (2,512,128,128)

    float* featsT = (float*)d_ws;                   // 8 * 262144 floats = 8 MB

    transpose_feats_kernel<<<BN_TOT * HF, 256, 0, stream>>>(feats, featsT);

    int nblk = BB * ZVOX * XVOX * 2;                // 4096 blocks, 64 voxels each
    bev_splat_kernel<<<nblk, 256, 0, stream>>>(featsT, intrins, extrins, out);
}

// Round 3
// 121.320 us; speedup vs baseline: 1.4416x; 1.4416x over previous
//
#include <hip/hip_runtime.h>

// Problem constants (fixed by the reference config)
#define BB     2
#define NN     4
#define CC     64
#define HF     64
#define WF     64
#define XVOX   128
#define YVOX   128
#define ZVOX   8
#define BN_TOT (BB * NN)                   // 8
#define FEATS_PER_BN (CC * HF * WF)        // 262144 floats
#define OUT_C_STRIDE (ZVOX * XVOX * YVOX)  // 131072
#define OUT_B_STRIDE (CC * OUT_C_STRIDE)   // 8388608

// ---------------------------------------------------------------------------
// Kernel 1: transpose feats NCHW -> NHWC so channels are contiguous.
// ---------------------------------------------------------------------------
__global__ __launch_bounds__(256) void transpose_feats_kernel(
    const float* __restrict__ in, float* __restrict__ outT) {
    __shared__ float tile[64 * 65];
    int bh = blockIdx.x;           // bn*64 + h
    int bn = bh >> 6;
    int h  = bh & 63;
    int t  = threadIdx.x;

    const float* src = in + bn * FEATS_PER_BN + h * WF;   // + c*4096 + w
#pragma unroll
    for (int k = 0; k < 16; ++k) {
        int idx = t + k * 256;     // 0..4095
        int c = idx >> 6;
        int w = idx & 63;
        tile[w * 65 + c] = src[c * (HF * WF) + w];        // coalesced read
    }
    __syncthreads();
    float* dst = outT + bn * FEATS_PER_BN + h * (WF * CC);  // + w*64 + c
#pragma unroll
    for (int k = 0; k < 16; ++k) {
        int idx = t + k * 256;
        int w = idx >> 6;
        int c = idx & 63;
        dst[w * CC + c] = tile[w * 65 + c];               // coalesced write
    }
}

// ---------------------------------------------------------------------------
// Kernel 2: main splat.
// Block = 256 threads = 4 waves, handles 64 consecutive vy voxels.
// Phase 1: thread t computes projection for (voxel t>>2, cam t&3) -> LDS
//          (all projection math in ONE parallel pass, ~80 VALU instrs/block).
// Phase 2: lane = channel; per (voxel,cam) read uniform offsets/weights from
//          LDS (broadcast) and do 4 coalesced 256B gathers + FMAs.
// Phase 3: LDS-staged coalesced stores of channel planes.
// ---------------------------------------------------------------------------
__global__ __launch_bounds__(256) void bev_splat_kernel(
    const float* __restrict__ featsT,   // (BN, H, W, C)
    const float* __restrict__ intrins,  // (BN, 4, 4)
    const float* __restrict__ extrins,  // (BN, 4, 4)
    float* __restrict__ out) {
    __shared__ float mats_s[NN * 12];
    __shared__ __align__(16) int   offs_s[64][NN][4];
    __shared__ __align__(16) float wgts_s[64][NN][4];
    __shared__ float tile[64 * 65];

    int blk  = blockIdx.x;         // ((b*ZVOX+vz)*XVOX+vx)*2 + half
    int half = blk & 1;
    int vx   = (blk >> 1) & 127;
    int vz   = (blk >> 8) & 7;
    int b    = blk >> 11;
    int vy0  = half * 64;

    // ---- phase 0: compose this batch's 4 projection matrices ----
    if (threadIdx.x < NN) {
        int n  = threadIdx.x;
        int bn = b * NN + n;
        const float* e = extrins + bn * 16;
        const float* k = intrins + bn * 16;
        float inv[3][4];
#pragma unroll
        for (int i = 0; i < 3; ++i) {
            inv[i][0] = e[0 * 4 + i];
            inv[i][1] = e[1 * 4 + i];
            inv[i][2] = e[2 * 4 + i];
            inv[i][3] = -(e[0 * 4 + i] * e[0 * 4 + 3] +
                          e[1 * 4 + i] * e[1 * 4 + 3] +
                          e[2 * 4 + i] * e[2 * 4 + 3]);
        }
        float fx = k[0] * 0.125f;   // K[0,0] * sx (sx = 64/512 exact)
        float fy = k[5] * 0.125f;
        float cx = k[2] * 0.125f;
        float cy = k[6] * 0.125f;
        float* m = mats_s + n * 12;
#pragma unroll
        for (int j = 0; j < 4; ++j) {
            m[j]     = fx * inv[0][j] + cx * inv[2][j];
            m[4 + j] = fy * inv[1][j] + cy * inv[2][j];
            m[8 + j] = inv[2][j];
        }
    }
    __syncthreads();

    // ---- phase 1: per-(voxel,cam) projection, fully lane-parallel ----
    {
        int v  = threadIdx.x >> 2;
        int n  = threadIdx.x & 3;
        int vy = vy0 + v;
        float xc = vx * 0.8f - 50.8f;
        float yc = vy * 0.8f - 50.8f;
        float zc = vz * 0.5f - 2.75f;
        const float* M = mats_s + n * 12;
        float px = M[0] * xc + M[1] * yc + M[2]  * zc + M[3];
        float py = M[4] * xc + M[5] * yc + M[6]  * zc + M[7];
        float pz = M[8] * xc + M[9] * yc + M[10] * zc + M[11];
        float denom = fmaxf(pz, 1e-6f);
        float sx = px / denom;
        float sy = py / denom;
        bool valid = (sx > -0.5f) && (sx < (float)WF - 0.5f) &&
                     (sy > -0.5f) && (sy < (float)HF - 0.5f) && (pz > 0.0f);
        int base = (b * NN + n) * FEATS_PER_BN;
        int   o[4];
        float w[4];
        if (valid) {
            float gx = sx - 0.5f;
            float gy = sy - 0.5f;
            float x0f = floorf(gx), y0f = floorf(gy);
            float wx = gx - x0f,    wy = gy - y0f;
            int x0 = (int)x0f, y0 = (int)y0f;
            int   xs[2]  = {x0, x0 + 1};
            int   ys[2]  = {y0, y0 + 1};
            float wxs[2] = {1.0f - wx, wx};
            float wys[2] = {1.0f - wy, wy};
#pragma unroll
            for (int ky = 0; ky < 2; ++ky) {
#pragma unroll
                for (int kx = 0; kx < 2; ++kx) {
                    int kk = ky * 2 + kx;   // corner order == reference order
                    int xi = xs[kx], yi = ys[ky];
                    bool cv = (xi >= 0) && (xi < WF) && (yi >= 0) && (yi < HF);
                    int xic = min(max(xi, 0), WF - 1);
                    int yic = min(max(yi, 0), HF - 1);
                    o[kk] = base + (yic * WF + xic) * CC;
                    w[kk] = cv ? (wxs[kx] * wys[ky]) : 0.0f;
                }
            }
        } else {
#pragma unroll
            for (int kk = 0; kk < 4; ++kk) { o[kk] = base; w[kk] = 0.0f; }
        }
#pragma unroll
        for (int kk = 0; kk < 4; ++kk) {
            offs_s[v][n][kk] = o[kk];
            wgts_s[v][n][kk] = w[kk];
        }
    }
    __syncthreads();

    // ---- phase 2: channel-per-lane coalesced gathers ----
    int wave = threadIdx.x >> 6;
    int lane = threadIdx.x & 63;   // = channel

    for (int i = 0; i < 16; ++i) {
        int v = wave * 16 + i;     // local voxel 0..63
        float num = 0.0f;
        float cnt = 0.0f;
#pragma unroll
        for (int n = 0; n < NN; ++n) {
            int4   o = *reinterpret_cast<const int4*>(&offs_s[v][n][0]);
            float4 w = *reinterpret_cast<const float4*>(&wgts_s[v][n][0]);
            float wsum = (w.x + w.y) + (w.z + w.w);   // weights >= 0
            if (wsum != 0.0f) {    // wave-uniform skip of invalid cams
                float val = w.x * featsT[o.x + lane];   // 256B coalesced
                val      += w.y * featsT[o.y + lane];
                val      += w.z * featsT[o.z + lane];
                val      += w.w * featsT[o.w + lane];
                num += val;
                cnt += (val != 0.0f) ? 1.0f : 0.0f;
            }
        }
        tile[v * 65 + lane] = num / (1e-6f + cnt);
    }
    __syncthreads();

    // ---- phase 3: coalesced store, 64 consecutive vy per channel plane ----
    int base = b * OUT_B_STRIDE + vz * (XVOX * YVOX) + vx * YVOX + vy0;
#pragma unroll
    for (int it = 0; it < 16; ++it) {
        int idx = threadIdx.x + it * 256;
        int c = idx >> 6;
        int v = idx & 63;
        out[base + c * OUT_C_STRIDE + v] = tile[v * 65 + c];
    }
}

// ---------------------------------------------------------------------------
extern "C" void kernel_launch(void* const* d_in, const int* in_sizes, int n_in,
                              void* d_out, int out_size, void* d_ws, size_t ws_size,
                              hipStream_t stream) {
    const float* feats   = (const float*)d_in[0];   // (2,4,64,64,64)
    const float* intrins = (const float*)d_in[1];   // (2,4,4,4)
    const float* extrins = (const float*)d_in[2];   // (2,4,4,4)
    float* out = (float*)d_out;                     // (2,512,128,128)

    float* featsT = (float*)d_ws;                   // 8 * 262144 floats = 8 MB

    transpose_feats_kernel<<<BN_TOT * HF, 256, 0, stream>>>(feats, featsT);

    int nblk = BB * ZVOX * XVOX * 2;                // 4096 blocks, 64 voxels each
    bev_splat_kernel<<<nblk, 256, 0, stream>>>(featsT, intrins, extrins, out);
}

// Round 4
// 100.388 us; speedup vs baseline: 1.7422x; 1.2085x over previous
//
#include <hip/hip_runtime.h>

// Problem constants (fixed by the reference config)
#define BB     2
#define NN     4
#define CC     64
#define HF     64
#define WF     64
#define XVOX   128
#define YVOX   128
#define ZVOX   8
#define BN_TOT (BB * NN)                   // 8
#define FEATS_PER_BN (CC * HF * WF)        // 262144 floats
#define OUT_C_STRIDE (ZVOX * XVOX * YVOX)  // 131072
#define OUT_B_STRIDE (CC * OUT_C_STRIDE)   // 8388608

// ---------------------------------------------------------------------------
// Kernel 1: transpose feats NCHW -> NHWC so channels are contiguous.
// ---------------------------------------------------------------------------
__global__ __launch_bounds__(256) void transpose_feats_kernel(
    const float* __restrict__ in, float* __restrict__ outT) {
    __shared__ float tile[64 * 65];
    int bh = blockIdx.x;           // bn*64 + h
    int bn = bh >> 6;
    int h  = bh & 63;
    int t  = threadIdx.x;

    const float* src = in + bn * FEATS_PER_BN + h * WF;   // + c*4096 + w
#pragma unroll
    for (int k = 0; k < 16; ++k) {
        int idx = t + k * 256;     // 0..4095
        int c = idx >> 6;
        int w = idx & 63;
        tile[w * 65 + c] = src[c * (HF * WF) + w];        // coalesced read
    }
    __syncthreads();
    float* dst = outT + bn * FEATS_PER_BN + h * (WF * CC);  // + w*64 + c
#pragma unroll
    for (int k = 0; k < 16; ++k) {
        int idx = t + k * 256;
        int w = idx >> 6;
        int c = idx & 63;
        dst[w * CC + c] = tile[w * 65 + c];               // coalesced write
    }
}

// ---------------------------------------------------------------------------
// Kernel 2: main splat.
// Block = 256 threads = 4 waves, handles 64 consecutive vy voxels.
// Phase 1: thread t computes projection for (voxel t>>2, cam t&3) -> LDS.
// Phase 2: lane = vsub*16 + lane16; lane owns 4 channels (float4) of voxel
//          vsub in each 4-voxel group -> one wave does 4 voxels per pass:
//          per (group, cam): 2 LDS b128 reads + 4 corner float4 gathers
//          (each one 1KB wave-load) + 16 FMAs. 4x fewer iterations, ~2.5x
//          fewer VALU ops than one-channel-per-lane.
// Phase 3: LDS-staged coalesced stores of channel planes.
// ---------------------------------------------------------------------------
__global__ __launch_bounds__(256) void bev_splat_kernel(
    const float* __restrict__ featsT,   // (BN, H, W, C)
    const float* __restrict__ intrins,  // (BN, 4, 4)
    const float* __restrict__ extrins,  // (BN, 4, 4)
    float* __restrict__ out) {
    __shared__ float mats_s[NN * 12];
    __shared__ __align__(16) int   offs_s[64][NN][4];
    __shared__ __align__(16) float wgts_s[64][NN][4];
    __shared__ float tile[64 * 65];

    // XCD-contiguous remap: HW round-robins blockIdx across 8 XCDs; this
    // gives each XCD a contiguous logical range (one b, 2 vz slices) so its
    // 4MB L2 holds the shared camera features. 4096 % 8 == 0 -> bijective.
    int blk = blockIdx.x;
    int lg  = ((blk & 7) << 9) | (blk >> 3);   // logical id 0..4095

    int half = lg & 1;
    int vx   = (lg >> 1) & 127;
    int vz   = (lg >> 8) & 7;
    int b    = lg >> 11;
    int vy0  = half * 64;

    // ---- phase 0: compose this batch's 4 projection matrices ----
    if (threadIdx.x < NN) {
        int n  = threadIdx.x;
        int bn = b * NN + n;
        const float* e = extrins + bn * 16;
        const float* k = intrins + bn * 16;
        float inv[3][4];
#pragma unroll
        for (int i = 0; i < 3; ++i) {
            inv[i][0] = e[0 * 4 + i];
            inv[i][1] = e[1 * 4 + i];
            inv[i][2] = e[2 * 4 + i];
            inv[i][3] = -(e[0 * 4 + i] * e[0 * 4 + 3] +
                          e[1 * 4 + i] * e[1 * 4 + 3] +
                          e[2 * 4 + i] * e[2 * 4 + 3]);
        }
        float fx = k[0] * 0.125f;   // K[0,0] * sx (sx = 64/512 exact)
        float fy = k[5] * 0.125f;
        float cx = k[2] * 0.125f;
        float cy = k[6] * 0.125f;
        float* m = mats_s + n * 12;
#pragma unroll
        for (int j = 0; j < 4; ++j) {
            m[j]     = fx * inv[0][j] + cx * inv[2][j];
            m[4 + j] = fy * inv[1][j] + cy * inv[2][j];
            m[8 + j] = inv[2][j];
        }
    }
    __syncthreads();

    // ---- phase 1: per-(voxel,cam) projection, fully lane-parallel ----
    {
        int v  = threadIdx.x >> 2;
        int n  = threadIdx.x & 3;
        int vy = vy0 + v;
        float xc = vx * 0.8f - 50.8f;
        float yc = vy * 0.8f - 50.8f;
        float zc = vz * 0.5f - 2.75f;
        const float* M = mats_s + n * 12;
        float px = M[0] * xc + M[1] * yc + M[2]  * zc + M[3];
        float py = M[4] * xc + M[5] * yc + M[6]  * zc + M[7];
        float pz = M[8] * xc + M[9] * yc + M[10] * zc + M[11];
        float denom = fmaxf(pz, 1e-6f);
        float sx = px / denom;
        float sy = py / denom;
        bool valid = (sx > -0.5f) && (sx < (float)WF - 0.5f) &&
                     (sy > -0.5f) && (sy < (float)HF - 0.5f) && (pz > 0.0f);
        int base = (b * NN + n) * FEATS_PER_BN;
        int   o[4];
        float w[4];
        if (valid) {
            float gx = sx - 0.5f;
            float gy = sy - 0.5f;
            float x0f = floorf(gx), y0f = floorf(gy);
            float wx = gx - x0f,    wy = gy - y0f;
            int x0 = (int)x0f, y0 = (int)y0f;
            int   xs[2]  = {x0, x0 + 1};
            int   ys[2]  = {y0, y0 + 1};
            float wxs[2] = {1.0f - wx, wx};
            float wys[2] = {1.0f - wy, wy};
#pragma unroll
            for (int ky = 0; ky < 2; ++ky) {
#pragma unroll
                for (int kx = 0; kx < 2; ++kx) {
                    int kk = ky * 2 + kx;   // corner order == reference order
                    int xi = xs[kx], yi = ys[ky];
                    bool cv = (xi >= 0) && (xi < WF) && (yi >= 0) && (yi < HF);
                    int xic = min(max(xi, 0), WF - 1);
                    int yic = min(max(yi, 0), HF - 1);
                    o[kk] = base + (yic * WF + xic) * CC;
                    w[kk] = cv ? (wxs[kx] * wys[ky]) : 0.0f;
                }
            }
        } else {
#pragma unroll
            for (int kk = 0; kk < 4; ++kk) { o[kk] = base; w[kk] = 0.0f; }
        }
#pragma unroll
        for (int kk = 0; kk < 4; ++kk) {
            offs_s[v][n][kk] = o[kk];
            wgts_s[v][n][kk] = w[kk];
        }
    }
    __syncthreads();

    // ---- phase 2: 4 voxels per wave-pass, float4 channels per lane ----
    int wave = threadIdx.x >> 6;
    int lane = threadIdx.x & 63;
    int l16  = lane & 15;          // channel block: channels l16*4 .. +3
    int vsub = lane >> 4;          // which voxel of the 4-group
    int coff = l16 << 2;           // float offset into the 64 channels

#pragma unroll
    for (int g = 0; g < 4; ++g) {
        int v = wave * 16 + g * 4 + vsub;    // this lane's local voxel
        float n0 = 0.f, n1 = 0.f, n2 = 0.f, n3 = 0.f;
        float c0 = 0.f, c1 = 0.f, c2 = 0.f, c3 = 0.f;
#pragma unroll
        for (int n = 0; n < NN; ++n) {
            int4   o = *reinterpret_cast<const int4*>(&offs_s[v][n][0]);
            float4 w = *reinterpret_cast<const float4*>(&wgts_s[v][n][0]);
            float wsum = (w.x + w.y) + (w.z + w.w);   // weights >= 0
            if (__any(wsum != 0.0f)) {
                float4 ga = *reinterpret_cast<const float4*>(featsT + o.x + coff);
                float4 gb = *reinterpret_cast<const float4*>(featsT + o.y + coff);
                float4 gc = *reinterpret_cast<const float4*>(featsT + o.z + coff);
                float4 gd = *reinterpret_cast<const float4*>(featsT + o.w + coff);
                // same corner order & left-to-right accumulation as reference
                float v0 = w.x * ga.x; v0 += w.y * gb.x; v0 += w.z * gc.x; v0 += w.w * gd.x;
                float v1 = w.x * ga.y; v1 += w.y * gb.y; v1 += w.z * gc.y; v1 += w.w * gd.y;
                float v2 = w.x * ga.z; v2 += w.y * gb.z; v2 += w.z * gc.z; v2 += w.w * gd.z;
                float v3 = w.x * ga.w; v3 += w.y * gb.w; v3 += w.z * gc.w; v3 += w.w * gd.w;
                n0 += v0; n1 += v1; n2 += v2; n3 += v3;
                c0 += (v0 != 0.0f) ? 1.0f : 0.0f;
                c1 += (v1 != 0.0f) ? 1.0f : 0.0f;
                c2 += (v2 != 0.0f) ? 1.0f : 0.0f;
                c3 += (v3 != 0.0f) ? 1.0f : 0.0f;
            }
        }
        float* tr = tile + v * 65 + coff;
        tr[0] = n0 / (1e-6f + c0);
        tr[1] = n1 / (1e-6f + c1);
        tr[2] = n2 / (1e-6f + c2);
        tr[3] = n3 / (1e-6f + c3);
    }
    __syncthreads();

    // ---- phase 3: coalesced store, 64 consecutive vy per channel plane ----
    int base = b * OUT_B_STRIDE + vz * (XVOX * YVOX) + vx * YVOX + vy0;
#pragma unroll
    for (int it = 0; it < 16; ++it) {
        int idx = threadIdx.x + it * 256;
        int c = idx >> 6;
        int v = idx & 63;
        out[base + c * OUT_C_STRIDE + v] = tile[v * 65 + c];
    }
}

// ---------------------------------------------------------------------------
extern "C" void kernel_launch(void* const* d_in, const int* in_sizes, int n_in,
                              void* d_out, int out_size, void* d_ws, size_t ws_size,
                              hipStream_t stream) {
    const float* feats   = (const float*)d_in[0];   // (2,4,64,64,64)
    const float* intrins = (const float*)d_in[1];   // (2,4,4,4)
    const float* extrins = (const float*)d_in[2];   // (2,4,4,4)
    float* out = (float*)d_out;                     // (2,512,128,128)

    float* featsT = (float*)d_ws;                   // 8 * 262144 floats = 8 MB

    transpose_feats_kernel<<<BN_TOT * HF, 256, 0, stream>>>(feats, featsT);

    int nblk = BB * ZVOX * XVOX * 2;                // 4096 blocks, 64 voxels each
    bev_splat_kernel<<<nblk, 256, 0, stream>>>(featsT, intrins, extrins, out);
}

// Round 5
// 100.036 us; speedup vs baseline: 1.7483x; 1.0035x over previous
//
#include <hip/hip_runtime.h>

// Problem constants (fixed by the reference config)
#define BB     2
#define NN     4
#define CC     64
#define HF     64
#define WF     64
#define XVOX   128
#define YVOX   128
#define ZVOX   8
#define BN_TOT (BB * NN)                   // 8
#define FEATS_PER_BN (CC * HF * WF)        // 262144 floats
#define OUT_C_STRIDE (ZVOX * XVOX * YVOX)  // 131072
#define OUT_B_STRIDE (CC * OUT_C_STRIDE)   // 8388608

// ---------------------------------------------------------------------------
// Kernel 1: transpose feats NCHW -> NHWC so channels are contiguous.
// ---------------------------------------------------------------------------
__global__ __launch_bounds__(256) void transpose_feats_kernel(
    const float* __restrict__ in, float* __restrict__ outT) {
    __shared__ float tile[64 * 65];
    int bh = blockIdx.x;           // bn*64 + h
    int bn = bh >> 6;
    int h  = bh & 63;
    int t  = threadIdx.x;

    const float* src = in + bn * FEATS_PER_BN + h * WF;   // + c*4096 + w
#pragma unroll
    for (int k = 0; k < 16; ++k) {
        int idx = t + k * 256;     // 0..4095
        int c = idx >> 6;
        int w = idx & 63;
        tile[w * 65 + c] = src[c * (HF * WF) + w];        // coalesced read
    }
    __syncthreads();
    float* dst = outT + bn * FEATS_PER_BN + h * (WF * CC);  // + w*64 + c
#pragma unroll
    for (int k = 0; k < 16; ++k) {
        int idx = t + k * 256;
        int w = idx >> 6;
        int c = idx & 63;
        dst[w * CC + c] = tile[w * 65 + c];               // coalesced write
    }
}

// ---------------------------------------------------------------------------
// Kernel 2: main splat.
// Block = 256 threads = 4 waves, handles 64 consecutive vy voxels.
// Phase 1: thread t computes projection for (voxel t>>2, cam t&3) -> LDS;
//          __syncthreads_count gives a block-wide validity count.
//          If zero: store 4096 zeros (float4, coalesced) and exit.
// Phase 2: lane = vsub*16 + l16; lane owns 4 channels (float4) of voxel vsub
//          in each 4-voxel group. Per-lane `wsum != 0` predication: invalid
//          voxel subgroups are exec-masked -> their memory requests never
//          issue (gather bytes scale with the valid fraction only).
// Phase 3: LDS-staged float4 stores of channel planes.
// ---------------------------------------------------------------------------
__global__ __launch_bounds__(256) void bev_splat_kernel(
    const float* __restrict__ featsT,   // (BN, H, W, C)
    const float* __restrict__ intrins,  // (BN, 4, 4)
    const float* __restrict__ extrins,  // (BN, 4, 4)
    float* __restrict__ out) {
    __shared__ float mats_s[NN * 12];
    __shared__ __align__(16) int   offs_s[64][NN][4];
    __shared__ __align__(16) float wgts_s[64][NN][4];
    __shared__ float tile[64 * 65];

    // XCD-contiguous remap (4096 % 8 == 0 -> bijective): each XCD gets one
    // batch's 4MB of featsT resident in its private L2.
    int blk = blockIdx.x;
    int lg  = ((blk & 7) << 9) | (blk >> 3);   // logical id 0..4095

    int half = lg & 1;
    int vx   = (lg >> 1) & 127;
    int vz   = (lg >> 8) & 7;
    int b    = lg >> 11;
    int vy0  = half * 64;

    // ---- phase 0: compose this batch's 4 projection matrices ----
    if (threadIdx.x < NN) {
        int n  = threadIdx.x;
        int bn = b * NN + n;
        const float* e = extrins + bn * 16;
        const float* k = intrins + bn * 16;
        float inv[3][4];
#pragma unroll
        for (int i = 0; i < 3; ++i) {
            inv[i][0] = e[0 * 4 + i];
            inv[i][1] = e[1 * 4 + i];
            inv[i][2] = e[2 * 4 + i];
            inv[i][3] = -(e[0 * 4 + i] * e[0 * 4 + 3] +
                          e[1 * 4 + i] * e[1 * 4 + 3] +
                          e[2 * 4 + i] * e[2 * 4 + 3]);
        }
        float fx = k[0] * 0.125f;   // K[0,0] * sx (sx = 64/512 exact)
        float fy = k[5] * 0.125f;
        float cx = k[2] * 0.125f;
        float cy = k[6] * 0.125f;
        float* m = mats_s + n * 12;
#pragma unroll
        for (int j = 0; j < 4; ++j) {
            m[j]     = fx * inv[0][j] + cx * inv[2][j];
            m[4 + j] = fy * inv[1][j] + cy * inv[2][j];
            m[8 + j] = inv[2][j];
        }
    }
    __syncthreads();

    // ---- phase 1: per-(voxel,cam) projection, fully lane-parallel ----
    bool validFlag;
    {
        int v  = threadIdx.x >> 2;
        int n  = threadIdx.x & 3;
        int vy = vy0 + v;
        float xc = vx * 0.8f - 50.8f;
        float yc = vy * 0.8f - 50.8f;
        float zc = vz * 0.5f - 2.75f;
        const float* M = mats_s + n * 12;
        float px = M[0] * xc + M[1] * yc + M[2]  * zc + M[3];
        float py = M[4] * xc + M[5] * yc + M[6]  * zc + M[7];
        float pz = M[8] * xc + M[9] * yc + M[10] * zc + M[11];
        float denom = fmaxf(pz, 1e-6f);
        float sx = px / denom;
        float sy = py / denom;
        bool valid = (sx > -0.5f) && (sx < (float)WF - 0.5f) &&
                     (sy > -0.5f) && (sy < (float)HF - 0.5f) && (pz > 0.0f);
        validFlag = valid;
        int base = (b * NN + n) * FEATS_PER_BN;
        int   o[4];
        float w[4];
        if (valid) {
            float gx = sx - 0.5f;
            float gy = sy - 0.5f;
            float x0f = floorf(gx), y0f = floorf(gy);
            float wx = gx - x0f,    wy = gy - y0f;
            int x0 = (int)x0f, y0 = (int)y0f;
            int   xs[2]  = {x0, x0 + 1};
            int   ys[2]  = {y0, y0 + 1};
            float wxs[2] = {1.0f - wx, wx};
            float wys[2] = {1.0f - wy, wy};
#pragma unroll
            for (int ky = 0; ky < 2; ++ky) {
#pragma unroll
                for (int kx = 0; kx < 2; ++kx) {
                    int kk = ky * 2 + kx;   // corner order == reference order
                    int xi = xs[kx], yi = ys[ky];
                    bool cv = (xi >= 0) && (xi < WF) && (yi >= 0) && (yi < HF);
                    int xic = min(max(xi, 0), WF - 1);
                    int yic = min(max(yi, 0), HF - 1);
                    o[kk] = base + (yic * WF + xic) * CC;
                    w[kk] = cv ? (wxs[kx] * wys[ky]) : 0.0f;
                }
            }
        } else {
#pragma unroll
            for (int kk = 0; kk < 4; ++kk) { o[kk] = base; w[kk] = 0.0f; }
        }
#pragma unroll
        for (int kk = 0; kk < 4; ++kk) {
            offs_s[v][n][kk] = o[kk];
            wgts_s[v][n][kk] = w[kk];
        }
    }

    int nvalid = __syncthreads_count(validFlag ? 1 : 0);

    int obase = b * OUT_B_STRIDE + vz * (XVOX * YVOX) + vx * YVOX + vy0;

    if (nvalid == 0) {
        // whole block outside every frustum: sum=0,count=0 -> exact zeros
        float4 z = make_float4(0.f, 0.f, 0.f, 0.f);
#pragma unroll
        for (int it = 0; it < 4; ++it) {
            int l4 = threadIdx.x + it * 256;   // 0..1023
            int c  = l4 >> 4;                  // channel
            int v  = (l4 & 15) << 2;           // vy offset (multiple of 4)
            *reinterpret_cast<float4*>(out + obase + c * OUT_C_STRIDE + v) = z;
        }
        return;
    }

    // ---- phase 2: 4 voxels per wave-pass, float4 channels per lane ----
    int wave = threadIdx.x >> 6;
    int lane = threadIdx.x & 63;
    int l16  = lane & 15;          // channel block: channels l16*4 .. +3
    int vsub = lane >> 4;          // which voxel of the 4-group
    const float* fT = featsT + (l16 << 2);

#pragma unroll
    for (int g = 0; g < 4; ++g) {
        int v = wave * 16 + g * 4 + vsub;    // this lane's local voxel
        float n0 = 0.f, n1 = 0.f, n2 = 0.f, n3 = 0.f;
        float c0 = 0.f, c1 = 0.f, c2 = 0.f, c3 = 0.f;
#pragma unroll
        for (int n = 0; n < NN; ++n) {
            int4   o = *reinterpret_cast<const int4*>(&offs_s[v][n][0]);
            float4 w = *reinterpret_cast<const float4*>(&wgts_s[v][n][0]);
            float wsum = (w.x + w.y) + (w.z + w.w);   // weights >= 0
            if (wsum != 0.0f) {   // per-voxel-subgroup exec mask: invalid
                                  // lanes issue NO memory requests
                float4 ga = *reinterpret_cast<const float4*>(fT + o.x);
                float4 gb = *reinterpret_cast<const float4*>(fT + o.y);
                float4 gc = *reinterpret_cast<const float4*>(fT + o.z);
                float4 gd = *reinterpret_cast<const float4*>(fT + o.w);
                // same corner order & left-to-right accumulation as reference
                float v0 = w.x * ga.x; v0 += w.y * gb.x; v0 += w.z * gc.x; v0 += w.w * gd.x;
                float v1 = w.x * ga.y; v1 += w.y * gb.y; v1 += w.z * gc.y; v1 += w.w * gd.y;
                float v2 = w.x * ga.z; v2 += w.y * gb.z; v2 += w.z * gc.z; v2 += w.w * gd.z;
                float v3 = w.x * ga.w; v3 += w.y * gb.w; v3 += w.z * gc.w; v3 += w.w * gd.w;
                n0 += v0; n1 += v1; n2 += v2; n3 += v3;
                c0 += (v0 != 0.0f) ? 1.0f : 0.0f;
                c1 += (v1 != 0.0f) ? 1.0f : 0.0f;
                c2 += (v2 != 0.0f) ? 1.0f : 0.0f;
                c3 += (v3 != 0.0f) ? 1.0f : 0.0f;
            }
        }
        float* tr = tile + v * 65 + (l16 << 2);
        tr[0] = n0 / (1e-6f + c0);
        tr[1] = n1 / (1e-6f + c1);
        tr[2] = n2 / (1e-6f + c2);
        tr[3] = n3 / (1e-6f + c3);
    }
    __syncthreads();

    // ---- phase 3: float4 coalesced stores, 64 consecutive vy per plane ----
#pragma unroll
    for (int it = 0; it < 4; ++it) {
        int l4 = threadIdx.x + it * 256;   // 0..1023
        int c  = l4 >> 4;
        int v  = (l4 & 15) << 2;
        float4 r;
        r.x = tile[(v + 0) * 65 + c];
        r.y = tile[(v + 1) * 65 + c];
        r.z = tile[(v + 2) * 65 + c];
        r.w = tile[(v + 3) * 65 + c];
        *reinterpret_cast<float4*>(out + obase + c * OUT_C_STRIDE + v) = r;
    }
}

// ---------------------------------------------------------------------------
extern "C" void kernel_launch(void* const* d_in, const int* in_sizes, int n_in,
                              void* d_out, int out_size, void* d_ws, size_t ws_size,
                              hipStream_t stream) {
    const float* feats   = (const float*)d_in[0];   // (2,4,64,64,64)
    const float* intrins = (const float*)d_in[1];   // (2,4,4,4)
    const float* extrins = (const float*)d_in[2];   // (2,4,4,4)
    float* out = (float*)d_out;                     // (2,512,128,128)

    float* featsT = (float*)d_ws;                   // 8 * 262144 floats = 8 MB

    transpose_feats_kernel<<<BN_TOT * HF, 256, 0, stream>>>(feats, featsT);

    int nblk = BB * ZVOX * XVOX * 2;                // 4096 blocks, 64 voxels each
    bev_splat_kernel<<<nblk, 256, 0, stream>>>(featsT, intrins, extrins, out);
}